// Round 3
// baseline (2221.725 us; speedup 1.0000x reference)
//
#include <hip/hip_runtime.h>
#include <hip/hip_cooperative_groups.h>
#include <stdint.h>

namespace cg = cooperative_groups;

#define Bc 8
#define Cc 64
#define Hc 256
#define Wc 256
#define Vc (Hc*Wc)            // 65536
#define REc ((Hc-1)*Wc)       // 65280 row edges
#define Ec (REc + Hc*(Wc-1))  // 130560 total edges
#define VM1 (Vc-1)            // 65535
#define INF64 0xFFFFFFFFFFFFFFFFull
#define MAXR 24
#define EPB 2048              // edges per block in compaction
#define BPB 64                // blocks per batch = ceil(Ec/EPB)

__device__ __forceinline__ void edge_uv(int e, int& u, int& v){
  if (e < REc){ u = e; v = e + Wc; }
  else { int k = e - REc; int i = k / (Wc-1); int j = k - i*(Wc-1); u = i*Wc + j; v = u + 1; }
}

__device__ __forceinline__ int chase(const int* __restrict__ parB, int x){
  int p = parB[x];
  while (p != x){ x = p; p = parB[x]; }
  return x;
}

__global__ void k_init(int* __restrict__ L, int* __restrict__ par,
                       unsigned long long* __restrict__ b0, unsigned long long* __restrict__ b1,
                       unsigned char* __restrict__ sel, int* __restrict__ act,
                       int* __restrict__ anyf, int* __restrict__ outp){
  int t = blockIdx.x*blockDim.x + threadIdx.x;
  if (t < Bc*Vc){ int v = t & VM1; L[t] = v; par[t] = v; b0[t] = INF64; b1[t] = INF64; }
  if (t < Bc*Ec) sel[t] = 0;
  if (t < Bc*VM1){ outp[2*t] = 0; outp[2*t+1] = Wc; }      // ref fill value (edge 0)
  if (t < (MAXR+2)*Bc) act[t] = (t < Bc) ? 1 : 0;
  if (t < MAXR+2) anyf[t] = 0;
}

// packed (weight_bits<<32 | edge_idx): lexicographic (w,e) min == u64 min
__global__ void k_weights(const float* __restrict__ g, unsigned long long* __restrict__ wp){
  int t = blockIdx.x*blockDim.x + threadIdx.x;
  if (t >= Bc*Ec) return;
  int b = t / Ec; int e = t - b*Ec;
  int u, v; edge_uv(e, u, v);
  const float* p = g + (size_t)b*Cc*Vc;
  float s = 0.f;
  #pragma unroll 8
  for (int c = 0; c < Cc; ++c){                            // sequential c order (bit-exact)
    float d = p[(size_t)c*Vc + u] - p[(size_t)c*Vc + v];
    s += d*d;
  }
  s += 1.0f;
  wp[t] = ((unsigned long long)__float_as_uint(s) << 32) | (unsigned)e;
}

// Cooperative fused Boruvka: per round {merge+scan} sync {hook} sync, double-buffered best.
__global__ void __launch_bounds__(256,4)
k_boruvka(const unsigned long long* __restrict__ wp, int* __restrict__ L,
          int* __restrict__ par,
          unsigned long long* __restrict__ b0, unsigned long long* __restrict__ b1,
          unsigned char* __restrict__ sel, int* __restrict__ act, int* __restrict__ anyf){
  cg::grid_group grid = cg::this_grid();
  const int gtid = blockIdx.x*256 + threadIdx.x;
  const int GS = gridDim.x*256;

  for (int r = 0; r < MAXR; ++r){
    unsigned long long* bcur = (r & 1) ? b1 : b0;
    unsigned long long* bnxt = (r & 1) ? b0 : b1;

    // --- phase A: (merge from previous hook) + vertex-centric scan, reset bnxt
    if (r == 0){
      for (int t = gtid; t < Bc*Vc; t += GS){
        int b = t >> 16; int v = t & VM1;
        int i = v >> 8, j = v & (Wc-1);
        const unsigned long long* wpb = wp + (size_t)b*Ec;
        unsigned long long m = INF64;
        if (i > 0)    { unsigned long long x = wpb[v - Wc];                 if (x < m) m = x; }
        if (i < Hc-1) { unsigned long long x = wpb[v];                      if (x < m) m = x; }
        if (j > 0)    { unsigned long long x = wpb[REc + i*(Wc-1) + j - 1]; if (x < m) m = x; }
        if (j < Wc-1) { unsigned long long x = wpb[REc + i*(Wc-1) + j];     if (x < m) m = x; }
        bcur[t] = m;                                       // distinct slots, no atomic needed
      }
    } else {
      for (int t = gtid; t < Bc*Vc; t += GS){
        int b = t >> 16;
        if (!act[r*Bc + b]) continue;
        int v = t & VM1; const int base = b << 16;
        const int* parB = par + base;
        int rt = chase(parB, L[t]);
        L[t] = rt;                                         // racy-read-benign: readers re-chase
        bnxt[t] = INF64;
        int i = v >> 8, j = v & (Wc-1);
        const unsigned long long* wpb = wp + (size_t)b*Ec;
        unsigned long long m = INF64;
        if (i > 0)    { int c = chase(parB, L[base + v - Wc]); if (c != rt){ unsigned long long x = wpb[v - Wc];                 if (x < m) m = x; } }
        if (i < Hc-1) { int c = chase(parB, L[base + v + Wc]); if (c != rt){ unsigned long long x = wpb[v];                      if (x < m) m = x; } }
        if (j > 0)    { int c = chase(parB, L[base + v - 1 ]); if (c != rt){ unsigned long long x = wpb[REc + i*(Wc-1) + j - 1]; if (x < m) m = x; } }
        if (j < Wc-1) { int c = chase(parB, L[base + v + 1 ]); if (c != rt){ unsigned long long x = wpb[REc + i*(Wc-1) + j];     if (x < m) m = x; } }
        if (m != INF64) atomicMin(&bcur[base + rt], m);
      }
    }
    grid.sync();

    // --- phase B: roots pick best edge, mutual-pair break, write par
    for (int t = gtid; t < Bc*Vc; t += GS){
      int b = t >> 16;
      if (!act[r*Bc + b]) continue;
      int v = t & VM1;
      if (L[t] != v) continue;                             // roots only
      const int base = b << 16;
      unsigned long long p = bcur[t];
      int pr = v;
      if (p != INF64){
        int e = (int)(unsigned)p; int eu, ev; edge_uv(e, eu, ev);
        int cu = L[base + eu], cv = L[base + ev];
        int other = (cu == v) ? cv : cu;
        sel[(size_t)b*Ec + e] = 1;
        act[(r+1)*Bc + b] = 1;                             // same-value racy store: fine
        anyf[r+1] = 1;
        pr = (bcur[base + other] == p && v < other) ? v : other;
      }
      par[t] = pr;
    }
    grid.sync();

    if (!anyf[r+1]) break;
  }
}

// ---- ordered output compaction: count -> per-batch offsets -> scatter ----
__global__ void __launch_bounds__(256)
k_cnt(const unsigned char* __restrict__ sel, int* __restrict__ blkcnt){
  int blk = blockIdx.x; int bb = blk >> 6; int kb = blk & (BPB-1);
  int base = kb*EPB;
  int lim = min(EPB, Ec - base);
  int off = threadIdx.x * 8;
  int c = 0;
  if (off < lim){
    const unsigned int* p = (const unsigned int*)(sel + (size_t)bb*Ec + base + off);
    unsigned int s = p[0] + p[1];                          // per-byte sums <=2, no carry
    c = (s & 0xFF) + ((s>>8)&0xFF) + ((s>>16)&0xFF) + (s>>24);
  }
  int lane = threadIdx.x & 63, wave = threadIdx.x >> 6;
  #pragma unroll
  for (int o = 32; o; o >>= 1) c += __shfl_down(c, o, 64);
  __shared__ int sw[4];
  if (lane == 0) sw[wave] = c;
  __syncthreads();
  if (threadIdx.x == 0) blkcnt[blk] = sw[0] + sw[1] + sw[2] + sw[3];
}

__global__ void __launch_bounds__(512)
k_off(const int* __restrict__ blkcnt, int* __restrict__ blkoff){
  int t = threadIdx.x;                                     // 512 = 8 batches x 64 blocks
  int lane = t & 63;
  int c = blkcnt[t];
  int x = c;
  #pragma unroll
  for (int o = 1; o < 64; o <<= 1){ int y = __shfl_up(x, o, 64); if (lane >= o) x += y; }
  blkoff[t] = x - c;                                       // exclusive within batch (wave==batch)
}

__global__ void __launch_bounds__(256)
k_scatter(const unsigned char* __restrict__ sel, const int* __restrict__ blkoff,
          int* __restrict__ outp){
  int blk = blockIdx.x; int bb = blk >> 6; int kb = blk & (BPB-1);
  int base = kb*EPB;
  int lim = min(EPB, Ec - base);
  int off = threadIdx.x * 8;
  unsigned int a = 0, d = 0; int c = 0;
  if (off < lim){
    const unsigned int* p = (const unsigned int*)(sel + (size_t)bb*Ec + base + off);
    a = p[0]; d = p[1];
    unsigned int s = a + d;
    c = (s & 0xFF) + ((s>>8)&0xFF) + ((s>>16)&0xFF) + (s>>24);
  }
  int lane = threadIdx.x & 63, wave = threadIdx.x >> 6;
  int x = c;
  #pragma unroll
  for (int o = 1; o < 64; o <<= 1){ int y = __shfl_up(x, o, 64); if (lane >= o) x += y; }
  __shared__ int sw[4];
  if (lane == 63) sw[wave] = x;
  __syncthreads();
  int woff = 0;
  #pragma unroll
  for (int w = 0; w < 4; ++w) if (w < wave) woff += sw[w];
  int pos = blkoff[blk] + woff + x - c;
  if (off < lim){
    int* ob = outp + (size_t)bb*VM1*2;
    int ebase = base + off;
    #pragma unroll
    for (int k = 0; k < 8; ++k){
      unsigned int byte = ((k < 4) ? (a >> (8*k)) : (d >> (8*(k-4)))) & 0xFF;
      if (byte){ int e = ebase + k; int u, v; edge_uv(e, u, v); ob[2*pos] = u; ob[2*pos+1] = v; ++pos; }
    }
  }
}

extern "C" void kernel_launch(void* const* d_in, const int* in_sizes, int n_in,
                              void* d_out, int out_size, void* d_ws, size_t ws_size,
                              hipStream_t stream) {
  const float* g = (const float*)d_in[0];
  int* outp = (int*)d_out;

  char* ws = (char*)d_ws;
  size_t off = 0;
  auto alloc = [&](size_t bytes) -> void* {
    void* p = ws + off; off += (bytes + 511) & ~(size_t)511; return p;
  };
  unsigned long long* b0 = (unsigned long long*)alloc((size_t)Bc*Vc*8);
  unsigned long long* b1 = (unsigned long long*)alloc((size_t)Bc*Vc*8);
  unsigned long long* wp = (unsigned long long*)alloc((size_t)Bc*Ec*8);
  int* L   = (int*)alloc((size_t)Bc*Vc*4);
  int* par = (int*)alloc((size_t)Bc*Vc*4);
  unsigned char* sel = (unsigned char*)alloc((size_t)Bc*Ec);
  int* act  = (int*)alloc((size_t)(MAXR+2)*Bc*4);
  int* anyf = (int*)alloc((size_t)(MAXR+2)*4);
  int* blkcnt = (int*)alloc((size_t)Bc*BPB*4);
  int* blkoff = (int*)alloc((size_t)Bc*BPB*4);

  k_init<<<(Bc*Ec + 255)/256, 256, 0, stream>>>(L, par, b0, b1, sel, act, anyf, outp);
  k_weights<<<(Bc*Ec + 255)/256, 256, 0, stream>>>(g, wp);

  void* kargs[] = { (void*)&wp, (void*)&L, (void*)&par, (void*)&b0, (void*)&b1,
                    (void*)&sel, (void*)&act, (void*)&anyf };
  hipLaunchCooperativeKernel((void*)k_boruvka, dim3(1024), dim3(256), kargs, 0, stream);

  k_cnt    <<<Bc*BPB, 256, 0, stream>>>(sel, blkcnt);
  k_off    <<<1, 512, 0, stream>>>(blkcnt, blkoff);
  k_scatter<<<Bc*BPB, 256, 0, stream>>>(sel, blkoff, outp);
}

// Round 4
// 278.580 us; speedup vs baseline: 7.9752x; 7.9752x over previous
//
#include <hip/hip_runtime.h>
#include <stdint.h>

#define Bc 8
#define Cc 64
#define Hc 256
#define Wc 256
#define Vc (Hc*Wc)            // 65536
#define REc ((Hc-1)*Wc)       // 65280 row edges
#define Ec (REc + Hc*(Wc-1))  // 130560 total edges
#define VM1 (Vc-1)            // 65535
#define INF64 0xFFFFFFFFFFFFFFFFull
#define NRND 16               // components at least halve per round; 2^16 = V
#define EPB 2048              // edges per block in compaction
#define BPB 64                // blocks per batch = ceil(Ec/EPB)

__device__ __forceinline__ void edge_uv(int e, int& u, int& v){
  if (e < REc){ u = e; v = e + Wc; }
  else { int k = e - REc; int i = k / (Wc-1); int j = k - i*(Wc-1); u = i*Wc + j; v = u + 1; }
}

__device__ __forceinline__ int chase(const int* __restrict__ parB, int x){
  int p = parB[x];
  while (p != x){ x = p; p = parB[x]; }
  return x;
}

__global__ void k_init(int* __restrict__ L, int* __restrict__ par,
                       unsigned long long* __restrict__ b0, unsigned long long* __restrict__ b1,
                       unsigned char* __restrict__ sel, int* __restrict__ act,
                       int* __restrict__ outp){
  int t = blockIdx.x*blockDim.x + threadIdx.x;
  if (t < Bc*Vc){ int v = t & VM1; L[t] = v; par[t] = v; b0[t] = INF64; b1[t] = INF64; }
  if (t < Bc*Ec) sel[t] = 0;
  if (t < Bc*VM1){ outp[2*t] = 0; outp[2*t+1] = Wc; }      // ref fill value (edge 0)
  if (t < (NRND+2)*Bc) act[t] = 0;
}

// packed (weight_bits<<32 | edge_idx): lexicographic (w,e) min == u64 min
__global__ void k_weights(const float* __restrict__ g, unsigned long long* __restrict__ wp){
  int t = blockIdx.x*blockDim.x + threadIdx.x;
  if (t >= Bc*Ec) return;
  int b = t / Ec; int e = t - b*Ec;
  int u, v; edge_uv(e, u, v);
  const float* p = g + (size_t)b*Cc*Vc;
  float s = 0.f;
  #pragma unroll 8
  for (int c = 0; c < Cc; ++c){                            // sequential c order (bit-exact)
    float d = p[(size_t)c*Vc + u] - p[(size_t)c*Vc + v];
    s += d*d;
  }
  s += 1.0f;
  wp[t] = ((unsigned long long)__float_as_uint(s) << 32) | (unsigned)e;
}

// round 0: identity labels -> per-vertex min over all 4 edges, direct write (no atomics)
__global__ void __launch_bounds__(256)
k_scan0(const unsigned long long* __restrict__ wp, unsigned long long* __restrict__ b0){
  int t = blockIdx.x*256 + threadIdx.x;
  int b = t >> 16; int v = t & VM1;
  int i = v >> 8, j = v & (Wc-1);
  const unsigned long long* wpb = wp + (size_t)b*Ec;
  unsigned long long m = INF64;
  if (i > 0)    { unsigned long long x = wpb[v - Wc];                 if (x < m) m = x; }
  if (i < Hc-1) { unsigned long long x = wpb[v];                      if (x < m) m = x; }
  if (j > 0)    { unsigned long long x = wpb[REc + i*(Wc-1) + j - 1]; if (x < m) m = x; }
  if (j < Wc-1) { unsigned long long x = wpb[REc + i*(Wc-1) + j];     if (x < m) m = x; }
  b0[t] = m;
}

// rounds >=1: fused {merge prev hook-forest into L} + {vertex-centric scan}, reset next buffer
__global__ void __launch_bounds__(256)
k_scanmerge(const unsigned long long* __restrict__ wp, int* __restrict__ L,
            const int* __restrict__ par,
            unsigned long long* __restrict__ bcur, unsigned long long* __restrict__ bnxt,
            const int* __restrict__ act, int r){
  int t = blockIdx.x*256 + threadIdx.x;
  int b = t >> 16;
  if (!act[r*Bc + b]) return;
  int v = t & VM1; const int base = b << 16;
  const int* parB = par + base;
  int Lt0 = L[t];
  int rt = chase(parB, Lt0);
  L[t] = rt;                                               // racy-read-benign: readers re-chase
  bnxt[t] = INF64;                                         // reset buffer for round r+1
  int i = v >> 8, j = v & (Wc-1);
  const unsigned long long* wpb = wp + (size_t)b*Ec;
  unsigned long long m = INF64;
  {
    if (i > 0){
      int Ln = L[base + v - Wc];
      if (Ln != Lt0 && Ln != rt && chase(parB, Ln) != rt){
        unsigned long long x = wpb[v - Wc]; if (x < m) m = x; }
    }
    if (i < Hc-1){
      int Ln = L[base + v + Wc];
      if (Ln != Lt0 && Ln != rt && chase(parB, Ln) != rt){
        unsigned long long x = wpb[v]; if (x < m) m = x; }
    }
    if (j > 0){
      int Ln = L[base + v - 1];
      if (Ln != Lt0 && Ln != rt && chase(parB, Ln) != rt){
        unsigned long long x = wpb[REc + i*(Wc-1) + j - 1]; if (x < m) m = x; }
    }
    if (j < Wc-1){
      int Ln = L[base + v + 1];
      if (Ln != Lt0 && Ln != rt && chase(parB, Ln) != rt){
        unsigned long long x = wpb[REc + i*(Wc-1) + j]; if (x < m) m = x; }
    }
  }
  if (m != INF64) atomicMin(&bcur[base + rt], m);
}

// roots pick best edge, mutual-pair break (smaller id stays root), write par + sel
__global__ void __launch_bounds__(256)
k_hook(const int* __restrict__ L, const unsigned long long* __restrict__ bcur,
       int* __restrict__ par, unsigned char* __restrict__ sel, int* __restrict__ act, int r){
  int t = blockIdx.x*256 + threadIdx.x;
  int b = t >> 16;
  if (r > 0 && !act[r*Bc + b]) return;
  int v = t & VM1;
  if (L[t] != v) return;                                   // roots only
  const int base = b << 16;
  unsigned long long p = bcur[t];
  int pr = v;
  if (p != INF64){
    int e = (int)(unsigned)p; int eu, ev; edge_uv(e, eu, ev);
    int cu = L[base + eu], cv = L[base + ev];
    int other = (cu == v) ? cv : cu;
    sel[(size_t)b*Ec + e] = 1;
    if (act[(r+1)*Bc + b] == 0) act[(r+1)*Bc + b] = 1;     // read-guarded, benign race
    pr = (bcur[base + other] == p && v < other) ? v : other;
  }
  par[t] = pr;
}

// ---- ordered output compaction: count -> per-batch offsets -> scatter ----
__global__ void __launch_bounds__(256)
k_cnt(const unsigned char* __restrict__ sel, int* __restrict__ blkcnt){
  int blk = blockIdx.x; int bb = blk >> 6; int kb = blk & (BPB-1);
  int base = kb*EPB;
  int lim = min(EPB, Ec - base);
  int off = threadIdx.x * 8;
  int c = 0;
  if (off < lim){
    const unsigned int* p = (const unsigned int*)(sel + (size_t)bb*Ec + base + off);
    unsigned int s = p[0] + p[1];                          // per-byte sums <=2, no carry
    c = (s & 0xFF) + ((s>>8)&0xFF) + ((s>>16)&0xFF) + (s>>24);
  }
  int lane = threadIdx.x & 63, wave = threadIdx.x >> 6;
  #pragma unroll
  for (int o = 32; o; o >>= 1) c += __shfl_down(c, o, 64);
  __shared__ int sw[4];
  if (lane == 0) sw[wave] = c;
  __syncthreads();
  if (threadIdx.x == 0) blkcnt[blk] = sw[0] + sw[1] + sw[2] + sw[3];
}

__global__ void __launch_bounds__(512)
k_off(const int* __restrict__ blkcnt, int* __restrict__ blkoff){
  int t = threadIdx.x;                                     // 512 = 8 batches x 64 blocks
  int lane = t & 63;
  int c = blkcnt[t];
  int x = c;
  #pragma unroll
  for (int o = 1; o < 64; o <<= 1){ int y = __shfl_up(x, o, 64); if (lane >= o) x += y; }
  blkoff[t] = x - c;                                       // exclusive within batch (wave==batch)
}

__global__ void __launch_bounds__(256)
k_scatter(const unsigned char* __restrict__ sel, const int* __restrict__ blkoff,
          int* __restrict__ outp){
  int blk = blockIdx.x; int bb = blk >> 6; int kb = blk & (BPB-1);
  int base = kb*EPB;
  int lim = min(EPB, Ec - base);
  int off = threadIdx.x * 8;
  unsigned int a = 0, d = 0; int c = 0;
  if (off < lim){
    const unsigned int* p = (const unsigned int*)(sel + (size_t)bb*Ec + base + off);
    a = p[0]; d = p[1];
    unsigned int s = a + d;
    c = (s & 0xFF) + ((s>>8)&0xFF) + ((s>>16)&0xFF) + (s>>24);
  }
  int lane = threadIdx.x & 63, wave = threadIdx.x >> 6;
  int x = c;
  #pragma unroll
  for (int o = 1; o < 64; o <<= 1){ int y = __shfl_up(x, o, 64); if (lane >= o) x += y; }
  __shared__ int sw[4];
  if (lane == 63) sw[wave] = x;
  __syncthreads();
  int woff = 0;
  #pragma unroll
  for (int w = 0; w < 4; ++w) if (w < wave) woff += sw[w];
  int pos = blkoff[blk] + woff + x - c;
  if (off < lim){
    int* ob = outp + (size_t)bb*VM1*2;
    int ebase = base + off;
    #pragma unroll
    for (int k = 0; k < 8; ++k){
      unsigned int byte = ((k < 4) ? (a >> (8*k)) : (d >> (8*(k-4)))) & 0xFF;
      if (byte){ int e = ebase + k; int u, v; edge_uv(e, u, v); ob[2*pos] = u; ob[2*pos+1] = v; ++pos; }
    }
  }
}

extern "C" void kernel_launch(void* const* d_in, const int* in_sizes, int n_in,
                              void* d_out, int out_size, void* d_ws, size_t ws_size,
                              hipStream_t stream) {
  const float* g = (const float*)d_in[0];
  int* outp = (int*)d_out;

  char* ws = (char*)d_ws;
  size_t off = 0;
  auto alloc = [&](size_t bytes) -> void* {
    void* p = ws + off; off += (bytes + 511) & ~(size_t)511; return p;
  };
  unsigned long long* b0 = (unsigned long long*)alloc((size_t)Bc*Vc*8);
  unsigned long long* b1 = (unsigned long long*)alloc((size_t)Bc*Vc*8);
  unsigned long long* wp = (unsigned long long*)alloc((size_t)Bc*Ec*8);
  int* L   = (int*)alloc((size_t)Bc*Vc*4);
  int* par = (int*)alloc((size_t)Bc*Vc*4);
  unsigned char* sel = (unsigned char*)alloc((size_t)Bc*Ec);
  int* act  = (int*)alloc((size_t)(NRND+2)*Bc*4);
  int* blkcnt = (int*)alloc((size_t)Bc*BPB*4);
  int* blkoff = (int*)alloc((size_t)Bc*BPB*4);

  const int gv = (Bc*Vc + 255)/256;                        // 2048 blocks, vertex-grids

  k_init<<<(Bc*Ec + 255)/256, 256, 0, stream>>>(L, par, b0, b1, sel, act, outp);
  k_weights<<<(Bc*Ec + 255)/256, 256, 0, stream>>>(g, wp);

  k_scan0<<<gv, 256, 0, stream>>>(wp, b0);
  k_hook <<<gv, 256, 0, stream>>>(L, b0, par, sel, act, 0);
  for (int r = 1; r < NRND; ++r){
    unsigned long long* bcur = (r & 1) ? b1 : b0;
    unsigned long long* bnxt = (r & 1) ? b0 : b1;
    k_scanmerge<<<gv, 256, 0, stream>>>(wp, L, par, bcur, bnxt, act, r);
    k_hook     <<<gv, 256, 0, stream>>>(L, bcur, par, sel, act, r);
  }

  k_cnt    <<<Bc*BPB, 256, 0, stream>>>(sel, blkcnt);
  k_off    <<<1, 512, 0, stream>>>(blkcnt, blkoff);
  k_scatter<<<Bc*BPB, 256, 0, stream>>>(sel, blkoff, outp);
}

// Round 5
// 271.795 us; speedup vs baseline: 8.1743x; 1.0250x over previous
//
#include <hip/hip_runtime.h>
#include <stdint.h>

#define Bc 8
#define Cc 64
#define Hc 256
#define Wc 256
#define Vc (Hc*Wc)            // 65536
#define REc ((Hc-1)*Wc)       // 65280 row (down) edges
#define Ec (REc + Hc*(Wc-1))  // 130560 total edges
#define VM1 (Vc-1)            // 65535
#define INF64 0xFFFFFFFFFFFFFFFFull
#define NRND 16               // components at least halve per round; 2^16 = V
#define EPB 2048              // edges per block in compaction
#define BPB 64                // blocks per batch = ceil(Ec/EPB)

__device__ __forceinline__ void edge_uv(int e, int& u, int& v){
  if (e < REc){ u = e; v = e + Wc; }
  else { int k = e - REc; int i = k / (Wc-1); int j = k - i*(Wc-1); u = i*Wc + j; v = u + 1; }
}

__device__ __forceinline__ int chase(const int* __restrict__ parB, int x){
  int p = parB[x];
  while (p != x){ x = p; p = parB[x]; }
  return x;
}

// pixel-centric: one thread per (b, pixel) computes its right+down edge weights in one
// pass over g (single fetch of each element), and performs all one-time init.
__global__ void __launch_bounds__(256)
k_weights(const float* __restrict__ g, float* __restrict__ wf,
          int* __restrict__ L, int* __restrict__ par,
          unsigned long long* __restrict__ b1,
          unsigned char* __restrict__ sel, int* __restrict__ act,
          int* __restrict__ outp){
  int t = blockIdx.x*256 + threadIdx.x;                    // [0, B*V)
  int b = t >> 16; int v = t & VM1;
  int i = v >> 8, j = v & (Wc-1);
  const bool hasR = (j < Wc-1), hasD = (i < Hc-1);
  const int offR = hasR ? 1 : 0, offD = hasD ? Wc : 0;     // clamped: no OOB, no divergence
  const float* p = g + (size_t)b*Cc*Vc + v;
  float sr = 0.f, sd = 0.f;
  #pragma unroll 4
  for (int c = 0; c < Cc; ++c){                            // sequential c order (bit-exact)
    const float* pc = p + (size_t)c*Vc;
    float x = pc[0];
    float dr = x - pc[offR];                               // 0 when !hasR
    float dd = x - pc[offD];                               // 0 when !hasD
    sr += dr*dr; sd += dd*dd;
  }
  float* wfb = wf + (size_t)b*Ec;
  unsigned char* selb = sel + (size_t)b*Ec;
  int ce = REc + i*(Wc-1) + j;
  if (hasD){ wfb[v]  = sd + 1.0f; selb[v]  = 0; }
  if (hasR){ wfb[ce] = sr + 1.0f; selb[ce] = 0; }
  L[t] = v; par[t] = v; b1[t] = INF64;
  if (t < Bc*VM1){ outp[2*t] = 0; outp[2*t+1] = Wc; }      // ref fill value (edge 0)
  if (t < (NRND+2)*Bc) act[t] = 0;
}

// round 0: identity labels -> per-vertex min over its <=4 edges, direct write (no atomics)
__global__ void __launch_bounds__(256)
k_scan0(const float* __restrict__ wf, unsigned long long* __restrict__ b0){
  int t = blockIdx.x*256 + threadIdx.x;
  int b = t >> 16; int v = t & VM1;
  int i = v >> 8, j = v & (Wc-1);
  const float* wfb = wf + (size_t)b*Ec;
  unsigned long long m = INF64;
  if (i > 0)    { unsigned long long x = ((unsigned long long)__float_as_uint(wfb[v - Wc]) << 32) | (unsigned)(v - Wc);                 if (x < m) m = x; }
  if (i < Hc-1) { unsigned long long x = ((unsigned long long)__float_as_uint(wfb[v]) << 32) | (unsigned)v;                             if (x < m) m = x; }
  if (j > 0)    { int e = REc + i*(Wc-1) + j - 1; unsigned long long x = ((unsigned long long)__float_as_uint(wfb[e]) << 32) | (unsigned)e; if (x < m) m = x; }
  if (j < Wc-1) { int e = REc + i*(Wc-1) + j;     unsigned long long x = ((unsigned long long)__float_as_uint(wfb[e]) << 32) | (unsigned)e; if (x < m) m = x; }
  b0[t] = m;
}

// rounds >=1: fused {relabel to hook-forest root} + {vertex-centric scan}, root-only
// reset of next buffer, with settled-interior fast path.
__global__ void __launch_bounds__(256)
k_scanmerge(const float* __restrict__ wf, int* __restrict__ L,
            const int* __restrict__ par,
            unsigned long long* __restrict__ bcur, unsigned long long* __restrict__ bnxt,
            const int* __restrict__ act, int r){
  int t = blockIdx.x*256 + threadIdx.x;
  int b = t >> 16;
  if (!act[r*Bc + b]) return;
  int v = t & VM1; const int base = b << 16;
  const int* parB = par + base;
  int Lt0 = L[t];
  int i = v >> 8, j = v & (Wc-1);
  int Lu = (i > 0)    ? L[base + v - Wc] : Lt0;
  int Ld = (i < Hc-1) ? L[base + v + Wc] : Lt0;
  int Ll = (j > 0)    ? L[base + v - 1 ] : Lt0;
  int Lr = (j < Wc-1) ? L[base + v + 1 ] : Lt0;
  if ((Lu==Lt0) & (Ld==Lt0) & (Ll==Lt0) & (Lr==Lt0)){      // settled neighborhood
    if (Lt0 != v) return;                                  // interior non-root: done
    if (parB[v] == v){ bnxt[t] = INF64; return; }          // true root: reset next buf
    /* dead root (stale self-label): fall through to refresh L */
  }
  int rt = chase(parB, Lt0);
  if (rt != Lt0) L[t] = rt;                                // racy-read-benign: readers re-chase
  if (v == rt) bnxt[t] = INF64;                            // root-only reset for round r+1
  const float* wfb = wf + (size_t)b*Ec;
  unsigned long long m = INF64;
  if (Lu != Lt0 && Lu != rt && chase(parB, Lu) != rt){
    int e = v - Wc; unsigned long long x = ((unsigned long long)__float_as_uint(wfb[e]) << 32) | (unsigned)e; if (x < m) m = x; }
  if (Ld != Lt0 && Ld != rt && chase(parB, Ld) != rt){
    int e = v;      unsigned long long x = ((unsigned long long)__float_as_uint(wfb[e]) << 32) | (unsigned)e; if (x < m) m = x; }
  if (Ll != Lt0 && Ll != rt && chase(parB, Ll) != rt){
    int e = REc + i*(Wc-1) + j - 1; unsigned long long x = ((unsigned long long)__float_as_uint(wfb[e]) << 32) | (unsigned)e; if (x < m) m = x; }
  if (Lr != Lt0 && Lr != rt && chase(parB, Lr) != rt){
    int e = REc + i*(Wc-1) + j;     unsigned long long x = ((unsigned long long)__float_as_uint(wfb[e]) << 32) | (unsigned)e; if (x < m) m = x; }
  if (m != INF64) atomicMin(&bcur[base + rt], m);
}

// roots pick best edge, mutual-pair break (smaller id stays root), write par + sel
__global__ void __launch_bounds__(256)
k_hook(const int* __restrict__ L, const unsigned long long* __restrict__ bcur,
       int* __restrict__ par, unsigned char* __restrict__ sel, int* __restrict__ act, int r){
  int t = blockIdx.x*256 + threadIdx.x;
  int b = t >> 16;
  if (r > 0 && !act[r*Bc + b]) return;
  int v = t & VM1;
  if (L[t] != v) return;                                   // roots only (L fresh for roots)
  const int base = b << 16;
  unsigned long long p = bcur[t];
  int pr = v;
  if (p != INF64){
    int e = (int)(unsigned)p; int eu, ev; edge_uv(e, eu, ev);
    int cu = L[base + eu], cv = L[base + ev];
    int other = (cu == v) ? cv : cu;
    sel[(size_t)b*Ec + e] = 1;
    if (act[(r+1)*Bc + b] == 0) act[(r+1)*Bc + b] = 1;     // read-guarded, benign race
    pr = (bcur[base + other] == p && v < other) ? v : other;
  }
  par[t] = pr;
}

// ---- ordered output compaction: count -> scatter (offsets recomputed in-scatter) ----
__global__ void __launch_bounds__(256)
k_cnt(const unsigned char* __restrict__ sel, int* __restrict__ blkcnt){
  int blk = blockIdx.x; int bb = blk >> 6; int kb = blk & (BPB-1);
  int base = kb*EPB;
  int off = threadIdx.x * 8;
  int c = 0;
  if (base + off < Ec){
    const unsigned int* p = (const unsigned int*)(sel + (size_t)bb*Ec + base + off);
    unsigned int s = p[0] + p[1];                          // per-byte sums <=2, no carry
    c = (s & 0xFF) + ((s>>8)&0xFF) + ((s>>16)&0xFF) + (s>>24);
  }
  int lane = threadIdx.x & 63, wave = threadIdx.x >> 6;
  #pragma unroll
  for (int o = 32; o; o >>= 1) c += __shfl_down(c, o, 64);
  __shared__ int sw[4];
  if (lane == 0) sw[wave] = c;
  __syncthreads();
  if (threadIdx.x == 0) blkcnt[blk] = sw[0] + sw[1] + sw[2] + sw[3];
}

__global__ void __launch_bounds__(256)
k_scatter(const unsigned char* __restrict__ sel, const int* __restrict__ blkcnt,
          int* __restrict__ outp){
  int blk = blockIdx.x; int bb = blk >> 6; int kb = blk & (BPB-1);
  __shared__ int s_boff;
  if (threadIdx.x < 64){                                   // wave 0: prefix of batch counts
    int c = ((int)threadIdx.x < kb) ? blkcnt[bb*BPB + threadIdx.x] : 0;
    #pragma unroll
    for (int o = 32; o; o >>= 1) c += __shfl_down(c, o, 64);
    if (threadIdx.x == 0) s_boff = c;
  }
  int base = kb*EPB;
  int off = threadIdx.x * 8;
  unsigned int a = 0, d = 0; int c = 0;
  if (base + off < Ec){
    const unsigned int* p = (const unsigned int*)(sel + (size_t)bb*Ec + base + off);
    a = p[0]; d = p[1];
    unsigned int s = a + d;
    c = (s & 0xFF) + ((s>>8)&0xFF) + ((s>>16)&0xFF) + (s>>24);
  }
  int lane = threadIdx.x & 63, wave = threadIdx.x >> 6;
  int x = c;
  #pragma unroll
  for (int o = 1; o < 64; o <<= 1){ int y = __shfl_up(x, o, 64); if (lane >= o) x += y; }
  __shared__ int sw[4];
  if (lane == 63) sw[wave] = x;
  __syncthreads();
  int woff = 0;
  #pragma unroll
  for (int w = 0; w < 4; ++w) if (w < wave) woff += sw[w];
  int pos = s_boff + woff + x - c;
  if (base + off < Ec){
    int* ob = outp + (size_t)bb*VM1*2;
    int ebase = base + off;
    #pragma unroll
    for (int k = 0; k < 8; ++k){
      unsigned int byte = ((k < 4) ? (a >> (8*k)) : (d >> (8*(k-4)))) & 0xFF;
      if (byte){ int e = ebase + k; int u, v; edge_uv(e, u, v); ob[2*pos] = u; ob[2*pos+1] = v; ++pos; }
    }
  }
}

extern "C" void kernel_launch(void* const* d_in, const int* in_sizes, int n_in,
                              void* d_out, int out_size, void* d_ws, size_t ws_size,
                              hipStream_t stream) {
  const float* g = (const float*)d_in[0];
  int* outp = (int*)d_out;

  char* ws = (char*)d_ws;
  size_t off = 0;
  auto alloc = [&](size_t bytes) -> void* {
    void* p = ws + off; off += (bytes + 511) & ~(size_t)511; return p;
  };
  unsigned long long* b0 = (unsigned long long*)alloc((size_t)Bc*Vc*8);
  unsigned long long* b1 = (unsigned long long*)alloc((size_t)Bc*Vc*8);
  float* wf = (float*)alloc((size_t)Bc*Ec*4);
  int* L   = (int*)alloc((size_t)Bc*Vc*4);
  int* par = (int*)alloc((size_t)Bc*Vc*4);
  unsigned char* sel = (unsigned char*)alloc((size_t)Bc*Ec);
  int* act  = (int*)alloc((size_t)(NRND+2)*Bc*4);
  int* blkcnt = (int*)alloc((size_t)Bc*BPB*4);

  const int gv = (Bc*Vc)/256;                              // 2048 blocks, vertex-grids

  k_weights<<<gv, 256, 0, stream>>>(g, wf, L, par, b1, sel, act, outp);
  k_scan0  <<<gv, 256, 0, stream>>>(wf, b0);
  k_hook   <<<gv, 256, 0, stream>>>(L, b0, par, sel, act, 0);
  for (int r = 1; r < NRND; ++r){
    unsigned long long* bcur = (r & 1) ? b1 : b0;
    unsigned long long* bnxt = (r & 1) ? b0 : b1;
    k_scanmerge<<<gv, 256, 0, stream>>>(wf, L, par, bcur, bnxt, act, r);
    k_hook     <<<gv, 256, 0, stream>>>(L, bcur, par, sel, act, r);
  }

  k_cnt    <<<Bc*BPB, 256, 0, stream>>>(sel, blkcnt);
  k_scatter<<<Bc*BPB, 256, 0, stream>>>(sel, blkcnt, outp);
}